// Round 13
// baseline (343.487 us; speedup 1.0000x reference)
//
#include <hip/hip_runtime.h>

typedef unsigned short u16;
typedef unsigned int u32;
typedef __bf16 bf16x8 __attribute__((ext_vector_type(8)));
typedef float f32x4 __attribute__((ext_vector_type(4)));

// ---------- numerics helpers ----------

// f32 -> e4m3fn -> f32 roundtrip for r in [0, 448], RNE
__device__ __forceinline__ float e4m3_rne(float r) {
  if (r < 0.015625f) {            // subnormal range: grid step 2^-9
    return rintf(r * 512.0f) * (1.0f / 512.0f);
  }
  u32 u = __float_as_uint(r);
  u32 lsb = (u >> 20) & 1u;       // keep 3 mantissa bits, drop 20, RNE
  u += 0x7FFFFu + lsb;
  u &= 0xFFF00000u;
  return __uint_as_float(u);
}

// fp4 level select against per-block thresholds t[7] = mids * ss.
__device__ __forceinline__ float fp4_level(float a, const float* t) {
  return a < t[3] ? (a < t[1] ? (a < t[0] ? 0.0f : 0.5f)
                              : (a < t[2] ? 1.0f : 1.5f))
                  : (a < t[5] ? (a < t[4] ? 2.0f : 3.0f)
                              : (a < t[6] ? 4.0f : 6.0f));
}

__device__ __forceinline__ void gload_lds16(const u16* g, void* l) {
  __builtin_amdgcn_global_load_lds(
      (const __attribute__((address_space(1))) void*)g,
      (__attribute__((address_space(3))) void*)l, 16, 0, 0);
}

// ---------- merged amax partials (x blocks then w blocks; no atomics) ----------

#define AMX_XB 2048
#define AMX_WB 512

__global__ void __launch_bounds__(256) amax_merged_kernel(const float4* __restrict__ x4,
                                                          int n4x,
                                                          const float4* __restrict__ w4,
                                                          int n4w,
                                                          float* __restrict__ px,
                                                          float* __restrict__ pw) {
  const float4* p;
  float* part;
  int n4, b, nb;
  if (blockIdx.x < AMX_XB) {
    p = x4; part = px; n4 = n4x; b = blockIdx.x; nb = AMX_XB;
  } else {
    p = w4; part = pw; n4 = n4w; b = blockIdx.x - AMX_XB; nb = AMX_WB;
  }
  float m = 0.0f;
  int stride = nb * 256;
  for (int i = b * 256 + threadIdx.x; i < n4; i += stride) {
    float4 v = p[i];
    m = fmaxf(m, fmaxf(fmaxf(fabsf(v.x), fabsf(v.y)), fmaxf(fabsf(v.z), fabsf(v.w))));
  }
#pragma unroll
  for (int o = 32; o > 0; o >>= 1) m = fmaxf(m, __shfl_xor(m, o));
  __shared__ float red[4];
  int wid = threadIdx.x >> 6, lane = threadIdx.x & 63;
  if (lane == 0) red[wid] = m;
  __syncthreads();
  if (threadIdx.x == 0)
    part[b] = fmaxf(fmaxf(red[0], red[1]), fmaxf(red[2], red[3]));
}

__global__ void __launch_bounds__(256) finalize_kernel(const float* __restrict__ px,
                                                       const float* __restrict__ pw,
                                                       float* __restrict__ scal,
                                                       int nx, int nw) {
  int tid = threadIdx.x;
  float mx = 0.0f, mw = 0.0f;
  for (int i = tid; i < nx; i += 256) mx = fmaxf(mx, px[i]);
  for (int i = tid; i < nw; i += 256) mw = fmaxf(mw, pw[i]);
#pragma unroll
  for (int o = 32; o > 0; o >>= 1) {
    mx = fmaxf(mx, __shfl_xor(mx, o));
    mw = fmaxf(mw, __shfl_xor(mw, o));
  }
  __shared__ float rx[4], rw[4];
  int wid = tid >> 6, lane = tid & 63;
  if (lane == 0) { rx[wid] = mx; rw[wid] = mw; }
  __syncthreads();
  if (tid == 0) {
    scal[0] = fmaxf(fmaxf(rx[0], rx[1]), fmaxf(rx[2], rx[3]));
    scal[1] = fmaxf(fmaxf(rw[0], rw[1]), fmaxf(rw[2], rw[3]));
  }
}

// ---------- merged quantize: x part (1 thread / 16-elem block), w part (1 wave
// / 16x16 block). ----------

__global__ void __launch_bounds__(256) quant_merged_kernel(const float* __restrict__ x,
                                                           const float* __restrict__ w,
                                                           const float* __restrict__ scal,
                                                           u16* __restrict__ qx,
                                                           u16* __restrict__ qw,
                                                           int nxblocks, int ntc, int K) {
  if ((int)blockIdx.x < nxblocks) {
    int b = blockIdx.x * 256 + threadIdx.x;
    const float4* px = (const float4*)(x + (size_t)b * 16);
    float4 v[4];
    v[0] = px[0]; v[1] = px[1]; v[2] = px[2]; v[3] = px[3];
    float am = 0.0f;
    const float* vf = (const float*)v;
#pragma unroll
    for (int i = 0; i < 16; ++i) am = fmaxf(am, fabsf(vf[i]));

    float g = scal[0] / 2688.0f;                     // g_scale = amax/(448*6)
    float ratio = fminf(fmaxf((am / 6.0f) / g, 0.0f), 448.0f);
    float sq = e4m3_rne(ratio);                      // e4m3 block scale (f32 value)
    float s = sq * g;
    float ss = s > 0.0f ? s : 1.0f;
    float t[7] = {0.25f * ss, 0.75f * ss, 1.25f * ss, 1.75f * ss,
                  2.5f * ss, 3.5f * ss, 5.0f * ss};

    union { u16 h[16]; uint4 v4[2]; } ou;
#pragma unroll
    for (int i = 0; i < 16; ++i) {
      float qv = copysignf(fp4_level(fabsf(vf[i]), t) * sq, vf[i]);  // exact in bf16
      ou.h[i] = (u16)(__float_as_uint(qv) >> 16);
    }
    uint4* qd = (uint4*)(qx + (size_t)b * 16);
    qd[0] = ou.v4[0];
    qd[1] = ou.v4[1];
  } else {
    int wav = (blockIdx.x - nxblocks) * 4 + (threadIdx.x >> 6);
    int lane = threadIdx.x & 63;
    int tr = wav / ntc, tc = wav % ntc;
    int r = lane >> 2, c = (lane & 3) * 4;
    size_t off = (size_t)(tr * 16 + r) * K + tc * 16 + c;
    float4 v = *(const float4*)(w + off);
    float am = fmaxf(fmaxf(fabsf(v.x), fabsf(v.y)), fmaxf(fabsf(v.z), fabsf(v.w)));
#pragma unroll
    for (int o = 32; o > 0; o >>= 1) am = fmaxf(am, __shfl_xor(am, o));

    float g = scal[1] / 2688.0f;
    float ratio = fminf(fmaxf((am / 6.0f) / g, 0.0f), 448.0f);
    float sq = e4m3_rne(ratio);
    float s = sq * g;
    float ss = s > 0.0f ? s : 1.0f;
    float t[7] = {0.25f * ss, 0.75f * ss, 1.25f * ss, 1.75f * ss,
                  2.5f * ss, 3.5f * ss, 5.0f * ss};

    float vf[4] = {v.x, v.y, v.z, v.w};
    union { u16 h[4]; uint2 v2; } ou;
#pragma unroll
    for (int i = 0; i < 4; ++i) {
      float qv = copysignf(fp4_level(fabsf(vf[i]), t) * sq, vf[i]);
      ou.h[i] = (u16)(__float_as_uint(qv) >> 16);
    }
    *(uint2*)(qw + off) = ou.v2;
  }
}

// ---------- bf16 GEMM, 256x256 tile, BK=64, 8 waves, ONE barrier per K-tile,
// FINE-GRAINED stage interleave ----------
// R7/R11 structure (best measured: 241us, MfmaUtil 49.3, conflicts 0) with the
// 8 stage-loads split into 4 pairs issued BETWEEN MFMA quadrants (m196: coarse
// stage-issue without the per-phase ds_read || G::load || MFMA interleave
// costs 7-27%). A-pairs inside cluster 1, B-pairs inside cluster 2; the last
// pair still gets a full MFMA quadrant (~310 cy) of cover before the boundary
// vmcnt(0) (L2 hit ~200 cy; panels are L2-resident: FETCH 295MB/512 blocks).
// All else unchanged: both-sides row-XOR swizzle, asm ds_read_b128 +
// rule-18 lgkm(0)+sched_barrier, single boundary barrier for buffer handoff.

#define BM 256
#define BN 256
#define BK 64

__global__ void __launch_bounds__(512, 2) gemm_kernel(const u16* __restrict__ A,
                                                      const u16* __restrict__ B,
                                                      const float* __restrict__ bias,
                                                      const float* __restrict__ scal,
                                                      float* __restrict__ out,
                                                      int M, int N, int K) {
  extern __shared__ char lds[];   // [2][A:32768 | B:32768]
  const int tid = threadIdx.x;
  const int wid = tid >> 6, lane = tid & 63;
  const int fr = lane & 15, fc = lane >> 4;
  const int wm = wid >> 2, wn = wid & 3;     // 2 x 4 wave grid; 128x64 out per wave
  const int sw = (fr & 7) << 4;              // read-side XOR

  // bijective XCD-aware block swizzle
  int nwg = gridDim.x, bid = blockIdx.x;
  int q8 = nwg >> 3, r8 = nwg & 7;
  int xcd = bid & 7, loc = bid >> 3;
  int wg = (xcd < r8 ? xcd * (q8 + 1) : r8 * (q8 + 1) + (xcd - r8) * q8) + loc;
  int ntn = N / BN;
  int tm = wg / ntn, tn = wg % ntn;
  int brow = tm * BM, bcol = tn * BN;

  // staging sources (inverse-swizzled; LDS dests linear for gload_lds)
  const int srow = tid >> 3;
  const int scol = ((((tid & 7) << 4) ^ ((srow & 7) << 4)) >> 1);
  const u16* gA = A + (size_t)(brow + srow) * K + scol;
  const u16* gB = B + (size_t)(bcol + srow) * K + scol;
  const size_t K64r = (size_t)K * 64;   // 64-row chunk stride
  const int ldsOff = wid << 10;

// pair p of A staging: chunks 2p, 2p+1
#define STAGE_A2(buf, kt, p) do {                                             \
    gload_lds16(gA + (2 * (p)) * K64r + (kt), (buf) + (2 * (p)) * 8192 + ldsOff); \
    gload_lds16(gA + (2 * (p) + 1) * K64r + (kt), (buf) + (2 * (p) + 1) * 8192 + ldsOff); \
  } while (0)
#define STAGE_B2(buf, kt, p) do {                                             \
    gload_lds16(gB + (2 * (p)) * K64r + (kt), (buf) + 32768 + (2 * (p)) * 8192 + ldsOff); \
    gload_lds16(gB + (2 * (p) + 1) * K64r + (kt), (buf) + 32768 + (2 * (p) + 1) * 8192 + ldsOff); \
  } while (0)

  // asm ds_read addresses (byte offsets in LDS address space)
  const u32 ldsbase = (u32)(uintptr_t)(__attribute__((address_space(3))) char*)lds;
  const u32 cb0 = (u32)((fc << 4) ^ sw);
  const u32 cb1 = cb0 ^ 64u;
  const u32 aB0 = ldsbase + (u32)((wm * 128 + fr) * 128) + cb0;
  const u32 aB1 = ldsbase + (u32)((wm * 128 + fr) * 128) + cb1;
  const u32 bB0 = ldsbase + 32768u + (u32)((wn * 64 + fr) * 128) + cb0;
  const u32 bB1 = ldsbase + 32768u + (u32)((wn * 64 + fr) * 128) + cb1;

#define DSR(dst, ad, off) \
  asm volatile("ds_read_b128 %0, %1 offset:" off : "=v"(dst) : "v"(ad))

#define LOAD_A0(dst) do { \
  DSR(dst[0][0], aC0, "0");    DSR(dst[0][1], aC1, "0");    \
  DSR(dst[1][0], aC0, "2048"); DSR(dst[1][1], aC1, "2048"); \
  DSR(dst[2][0], aC0, "4096"); DSR(dst[2][1], aC1, "4096"); \
  DSR(dst[3][0], aC0, "6144"); DSR(dst[3][1], aC1, "6144"); } while (0)
#define LOAD_A1(dst) do { \
  DSR(dst[0][0], aC0, "8192");  DSR(dst[0][1], aC1, "8192");  \
  DSR(dst[1][0], aC0, "10240"); DSR(dst[1][1], aC1, "10240"); \
  DSR(dst[2][0], aC0, "12288"); DSR(dst[2][1], aC1, "12288"); \
  DSR(dst[3][0], aC0, "14336"); DSR(dst[3][1], aC1, "14336"); } while (0)
#define LOAD_B0() do { \
  DSR(b0[0][0], bC0, "0");    DSR(b0[0][1], bC1, "0");    \
  DSR(b0[1][0], bC0, "2048"); DSR(b0[1][1], bC1, "2048"); } while (0)
#define LOAD_B1() do { \
  DSR(b1[0][0], bC0, "4096"); DSR(b1[0][1], bC1, "4096"); \
  DSR(b1[1][0], bC0, "6144"); DSR(b1[1][1], bC1, "6144"); } while (0)

#define MMA(qm, qn, af, bf)                                                  \
  _Pragma("unroll") for (int j_ = 0; j_ < 4; ++j_)                           \
  _Pragma("unroll") for (int n_ = 0; n_ < 2; ++n_)                           \
  _Pragma("unroll") for (int k_ = 0; k_ < 2; ++k_)                           \
    acc[(qm) * 4 + j_][(qn) * 2 + n_] = __builtin_amdgcn_mfma_f32_16x16x32_bf16( \
        af[j_][k_], bf[n_][k_], acc[(qm) * 4 + j_][(qn) * 2 + n_], 0, 0, 0);

#define LGK0()                                               \
  asm volatile("s_waitcnt lgkmcnt(0)" ::: "memory");         \
  __builtin_amdgcn_sched_barrier(0);
#define SB0() __builtin_amdgcn_sched_barrier(0);

  f32x4 acc[8][4];
  f32x4 zero = {0.0f, 0.0f, 0.0f, 0.0f};
#pragma unroll
  for (int m = 0; m < 8; ++m)
#pragma unroll
    for (int n = 0; n < 4; ++n) acc[m][n] = zero;

  const int NT = K / BK;

  // prologue: tile 0 -> buf0
  STAGE_A2(lds, 0, 0); STAGE_A2(lds, 0, 1);
  STAGE_B2(lds, 0, 0); STAGE_B2(lds, 0, 1);
  asm volatile("s_waitcnt vmcnt(0)" ::: "memory");
  __builtin_amdgcn_s_barrier();

  bf16x8 a[4][2], a2[4][2], b0[2][2], b1[2][2];
  int cur = 0;
  for (int t = 0; t < NT; ++t) {
    const u32 bo = (u32)(cur << 16);
    const u32 aC0 = aB0 + bo, aC1 = aB1 + bo;
    const u32 bC0 = bB0 + bo, bC1 = bB1 + bo;
    char* bq = lds + (cur ^ 1) * 65536;   // tile t+1's buffer
    const int kt1 = (t + 1) * BK;
    const int st1 = (t + 1 < NT);

    // cluster 1: reads for quads (0,0),(0,1); A-stage pairs interleaved
    // between the MFMA quadrants (fine-grained issue, m196)
    LOAD_A0(a);
    LOAD_B0();
    LOAD_B1();
    if (st1) STAGE_A2(bq, kt1, 0);
    LGK0();
    __builtin_amdgcn_s_setprio(1);
    MMA(0, 0, a, b0);
    __builtin_amdgcn_s_setprio(0);
    SB0();
    if (st1) STAGE_A2(bq, kt1, 1);
    SB0();
    __builtin_amdgcn_s_setprio(1);
    MMA(0, 1, a, b1);
    __builtin_amdgcn_s_setprio(0);
    SB0();

    // cluster 2: second A half into separate regs; B-stage pairs interleaved
    LOAD_A1(a2);
    if (st1) STAGE_B2(bq, kt1, 0);
    LGK0();
    __builtin_amdgcn_s_setprio(1);
    MMA(1, 1, a2, b1);
    __builtin_amdgcn_s_setprio(0);
    SB0();
    if (st1) STAGE_B2(bq, kt1, 1);
    SB0();
    __builtin_amdgcn_s_setprio(1);
    MMA(1, 0, a2, b0);
    __builtin_amdgcn_s_setprio(0);
    SB0();

    // tile boundary: retire t+1's stages, ONE block-wide barrier (handoff)
    asm volatile("s_waitcnt vmcnt(0)" ::: "memory");
    __builtin_amdgcn_s_barrier();
    __builtin_amdgcn_sched_barrier(0);
    cur ^= 1;
  }

  // epilogue: y = acc * (g_x * g_w) + bias
  float gs = (scal[0] / 2688.0f) * (scal[1] / 2688.0f);
#pragma unroll
  for (int n = 0; n < 4; ++n) {
    int col = bcol + wn * 64 + n * 16 + fr;        // C/D: col = lane&15
    float bv = bias[col];
#pragma unroll
    for (int m = 0; m < 8; ++m) {
      int row0 = brow + wm * 128 + m * 16 + (fc << 2);  // row = (lane>>4)*4 + j
      f32x4 v = acc[m][n];
#pragma unroll
      for (int j = 0; j < 4; ++j)
        out[(size_t)(row0 + j) * N + col] = v[j] * gs + bv;
    }
  }
}

// ---------- launch ----------

extern "C" void kernel_launch(void* const* d_in, const int* in_sizes, int n_in,
                              void* d_out, int out_size, void* d_ws, size_t ws_size,
                              hipStream_t stream) {
  const float* x = (const float*)d_in[0];
  const float* w = (const float*)d_in[1];
  const float* bias = (const float*)d_in[2];
  float* out = (float*)d_out;

  const int DOUT = in_sizes[2];        // 4096
  const int K = in_sizes[1] / DOUT;    // 4096
  const int M = in_sizes[0] / K;       // 8192
  const int N = DOUT;

  // ws layout: [0,8): scal; [256, +8KB): px; then pw (2KB); qw at 32768; qx after
  float* scal = (float*)d_ws;
  float* px = (float*)((char*)d_ws + 256);          // 2048 floats
  float* pw = px + 2048;                            // 512 floats
  u16* qw = (u16*)((char*)d_ws + 32768);
  u16* qx = (u16*)((char*)d_ws + 32768 + (size_t)N * K * 2);

  // pass 1: both amax partial reductions in ONE launch
  amax_merged_kernel<<<AMX_XB + AMX_WB, 256, 0, stream>>>(
      (const float4*)x, (M * K) / 4, (const float4*)w, (N * K) / 4, px, pw);
  finalize_kernel<<<1, 256, 0, stream>>>(px, pw, scal, AMX_XB, AMX_WB);

  // pass 2: both quantizations in ONE launch
  int nxblocks = (M * K) / 16 / 256;               // 8192
  int nwblocks = (N / 16) * (K / 16) / 4;          // 16384
  quant_merged_kernel<<<nxblocks + nwblocks, 256, 0, stream>>>(
      x, w, scal, qx, qw, nxblocks, K / 16, K);

  gemm_kernel<<<(M / BM) * (N / BN), 512, 131072, stream>>>(qx, qw, bias, scal, out,
                                                            M, N, K);
}

// Round 14
// 333.824 us; speedup vs baseline: 1.0289x; 1.0289x over previous
//
#include <hip/hip_runtime.h>

typedef unsigned short u16;
typedef unsigned int u32;
typedef __bf16 bf16x8 __attribute__((ext_vector_type(8)));
typedef float f32x4 __attribute__((ext_vector_type(4)));

// ---------- numerics helpers ----------

// f32 -> e4m3fn -> f32 roundtrip for r in [0, 448], RNE
__device__ __forceinline__ float e4m3_rne(float r) {
  if (r < 0.015625f) {            // subnormal range: grid step 2^-9
    return rintf(r * 512.0f) * (1.0f / 512.0f);
  }
  u32 u = __float_as_uint(r);
  u32 lsb = (u >> 20) & 1u;       // keep 3 mantissa bits, drop 20, RNE
  u += 0x7FFFFu + lsb;
  u &= 0xFFF00000u;
  return __uint_as_float(u);
}

// fp4 level select against per-block thresholds t[7] = mids * ss.
__device__ __forceinline__ float fp4_level(float a, const float* t) {
  return a < t[3] ? (a < t[1] ? (a < t[0] ? 0.0f : 0.5f)
                              : (a < t[2] ? 1.0f : 1.5f))
                  : (a < t[5] ? (a < t[4] ? 2.0f : 3.0f)
                              : (a < t[6] ? 4.0f : 6.0f));
}

__device__ __forceinline__ void gload_lds16(const u16* g, void* l) {
  __builtin_amdgcn_global_load_lds(
      (const __attribute__((address_space(1))) void*)g,
      (__attribute__((address_space(3))) void*)l, 16, 0, 0);
}

// ---------- merged amax partials (x blocks then w blocks; no atomics) ----------

#define AMX_XB 2048
#define AMX_WB 512

__global__ void __launch_bounds__(256) amax_merged_kernel(const float4* __restrict__ x4,
                                                          int n4x,
                                                          const float4* __restrict__ w4,
                                                          int n4w,
                                                          float* __restrict__ px,
                                                          float* __restrict__ pw) {
  const float4* p;
  float* part;
  int n4, b, nb;
  if (blockIdx.x < AMX_XB) {
    p = x4; part = px; n4 = n4x; b = blockIdx.x; nb = AMX_XB;
  } else {
    p = w4; part = pw; n4 = n4w; b = blockIdx.x - AMX_XB; nb = AMX_WB;
  }
  float m = 0.0f;
  int stride = nb * 256;
  for (int i = b * 256 + threadIdx.x; i < n4; i += stride) {
    float4 v = p[i];
    m = fmaxf(m, fmaxf(fmaxf(fabsf(v.x), fabsf(v.y)), fmaxf(fabsf(v.z), fabsf(v.w))));
  }
#pragma unroll
  for (int o = 32; o > 0; o >>= 1) m = fmaxf(m, __shfl_xor(m, o));
  __shared__ float red[4];
  int wid = threadIdx.x >> 6, lane = threadIdx.x & 63;
  if (lane == 0) red[wid] = m;
  __syncthreads();
  if (threadIdx.x == 0)
    part[b] = fmaxf(fmaxf(red[0], red[1]), fmaxf(red[2], red[3]));
}

__global__ void __launch_bounds__(256) finalize_kernel(const float* __restrict__ px,
                                                       const float* __restrict__ pw,
                                                       float* __restrict__ scal,
                                                       int nx, int nw) {
  int tid = threadIdx.x;
  float mx = 0.0f, mw = 0.0f;
  for (int i = tid; i < nx; i += 256) mx = fmaxf(mx, px[i]);
  for (int i = tid; i < nw; i += 256) mw = fmaxf(mw, pw[i]);
#pragma unroll
  for (int o = 32; o > 0; o >>= 1) {
    mx = fmaxf(mx, __shfl_xor(mx, o));
    mw = fmaxf(mw, __shfl_xor(mw, o));
  }
  __shared__ float rx[4], rw[4];
  int wid = tid >> 6, lane = tid & 63;
  if (lane == 0) { rx[wid] = mx; rw[wid] = mw; }
  __syncthreads();
  if (tid == 0) {
    scal[0] = fmaxf(fmaxf(rx[0], rx[1]), fmaxf(rx[2], rx[3]));
    scal[1] = fmaxf(fmaxf(rw[0], rw[1]), fmaxf(rw[2], rw[3]));
  }
}

// ---------- merged quantize: x part (1 thread / 16-elem block), w part (1 wave
// / 16x16 block). ----------

__global__ void __launch_bounds__(256) quant_merged_kernel(const float* __restrict__ x,
                                                           const float* __restrict__ w,
                                                           const float* __restrict__ scal,
                                                           u16* __restrict__ qx,
                                                           u16* __restrict__ qw,
                                                           int nxblocks, int ntc, int K) {
  if ((int)blockIdx.x < nxblocks) {
    int b = blockIdx.x * 256 + threadIdx.x;
    const float4* px = (const float4*)(x + (size_t)b * 16);
    float4 v[4];
    v[0] = px[0]; v[1] = px[1]; v[2] = px[2]; v[3] = px[3];
    float am = 0.0f;
    const float* vf = (const float*)v;
#pragma unroll
    for (int i = 0; i < 16; ++i) am = fmaxf(am, fabsf(vf[i]));

    float g = scal[0] / 2688.0f;                     // g_scale = amax/(448*6)
    float ratio = fminf(fmaxf((am / 6.0f) / g, 0.0f), 448.0f);
    float sq = e4m3_rne(ratio);                      // e4m3 block scale (f32 value)
    float s = sq * g;
    float ss = s > 0.0f ? s : 1.0f;
    float t[7] = {0.25f * ss, 0.75f * ss, 1.25f * ss, 1.75f * ss,
                  2.5f * ss, 3.5f * ss, 5.0f * ss};

    union { u16 h[16]; uint4 v4[2]; } ou;
#pragma unroll
    for (int i = 0; i < 16; ++i) {
      float qv = copysignf(fp4_level(fabsf(vf[i]), t) * sq, vf[i]);  // exact in bf16
      ou.h[i] = (u16)(__float_as_uint(qv) >> 16);
    }
    uint4* qd = (uint4*)(qx + (size_t)b * 16);
    qd[0] = ou.v4[0];
    qd[1] = ou.v4[1];
  } else {
    int wav = (blockIdx.x - nxblocks) * 4 + (threadIdx.x >> 6);
    int lane = threadIdx.x & 63;
    int tr = wav / ntc, tc = wav % ntc;
    int r = lane >> 2, c = (lane & 3) * 4;
    size_t off = (size_t)(tr * 16 + r) * K + tc * 16 + c;
    float4 v = *(const float4*)(w + off);
    float am = fmaxf(fmaxf(fabsf(v.x), fabsf(v.y)), fmaxf(fabsf(v.z), fabsf(v.w)));
#pragma unroll
    for (int o = 32; o > 0; o >>= 1) am = fmaxf(am, __shfl_xor(am, o));

    float g = scal[1] / 2688.0f;
    float ratio = fminf(fmaxf((am / 6.0f) / g, 0.0f), 448.0f);
    float sq = e4m3_rne(ratio);
    float s = sq * g;
    float ss = s > 0.0f ? s : 1.0f;
    float t[7] = {0.25f * ss, 0.75f * ss, 1.25f * ss, 1.75f * ss,
                  2.5f * ss, 3.5f * ss, 5.0f * ss};

    float vf[4] = {v.x, v.y, v.z, v.w};
    union { u16 h[4]; uint2 v2; } ou;
#pragma unroll
    for (int i = 0; i < 4; ++i) {
      float qv = copysignf(fp4_level(fabsf(vf[i]), t) * sq, vf[i]);
      ou.h[i] = (u16)(__float_as_uint(qv) >> 16);
    }
    *(uint2*)(qw + off) = ou.v2;
  }
}

// ---------- bf16 GEMM, 256x256 tile, BK=64, 8 waves, ONE barrier per K-tile ----
// Best-measured structure (241us GEMM, MfmaUtil 49.5, conflicts 0).
// Only the tile-boundary barrier is needed for correctness (buffer handoff):
//   - staging targets buf^1, whose tile-(t-1) readers all passed the boundary
//     barrier of tile t-1;
//   - reads of buf[cur] follow the vmcnt(0)+barrier that retired its stages.
// Within a tile, waves free-run: one wave's MFMA cluster overlaps another's
// ds_read burst (m114-style overlap on separate pipes).
// Swizzle (both-sides): element (row, byte b) at row*128 + (b ^ ((row&7)<<4)),
// staged via gload_lds with inverse-swizzled global source (linear LDS dest),
// read via asm ds_read_b128 with the same XOR + rule-18 lgkm(0)+sched_barrier.
// Two A-frag register sets (a, a2) avoid WAR between read cluster 2 and
// MFMA cluster 1; acc lives in AGPRs (unified file).
// Measured-null/negative on this structure (search log R3-R13): counted
// vmcnt (staging is L2-resident; drains ~200cy), reg-staging, cross-tile
// reads, progressive lgkm, 32x32x16 shape, 128^2 tile @ 2 blk/CU,
// wave-stagger, fine-grained stage interleave.

#define BM 256
#define BN 256
#define BK 64

__global__ void __launch_bounds__(512, 2) gemm_kernel(const u16* __restrict__ A,
                                                      const u16* __restrict__ B,
                                                      const float* __restrict__ bias,
                                                      const float* __restrict__ scal,
                                                      float* __restrict__ out,
                                                      int M, int N, int K) {
  extern __shared__ char lds[];   // [2][A:32768 | B:32768]
  const int tid = threadIdx.x;
  const int wid = tid >> 6, lane = tid & 63;
  const int fr = lane & 15, fc = lane >> 4;
  const int wm = wid >> 2, wn = wid & 3;     // 2 x 4 wave grid; 128x64 out per wave
  const int sw = (fr & 7) << 4;              // read-side XOR

  // bijective XCD-aware block swizzle
  int nwg = gridDim.x, bid = blockIdx.x;
  int q8 = nwg >> 3, r8 = nwg & 7;
  int xcd = bid & 7, loc = bid >> 3;
  int wg = (xcd < r8 ? xcd * (q8 + 1) : r8 * (q8 + 1) + (xcd - r8) * q8) + loc;
  int ntn = N / BN;
  int tm = wg / ntn, tn = wg % ntn;
  int brow = tm * BM, bcol = tn * BN;

  // staging sources (inverse-swizzled; LDS dests linear for gload_lds)
  const int srow = tid >> 3;
  const int scol = ((((tid & 7) << 4) ^ ((srow & 7) << 4)) >> 1);
  const u16* gA = A + (size_t)(brow + srow) * K + scol;
  const u16* gB = B + (size_t)(bcol + srow) * K + scol;
  const size_t K64r = (size_t)K * 64;   // 64-row chunk stride
  const int ldsOff = wid << 10;

#define STAGE_A4(buf, kt) do {                                                \
    gload_lds16(gA + (kt), (buf) + ldsOff);                                   \
    gload_lds16(gA + K64r + (kt), (buf) + 8192 + ldsOff);                     \
    gload_lds16(gA + 2 * K64r + (kt), (buf) + 16384 + ldsOff);                \
    gload_lds16(gA + 3 * K64r + (kt), (buf) + 24576 + ldsOff);                \
  } while (0)
#define STAGE_B4(buf, kt) do {                                                \
    gload_lds16(gB + (kt), (buf) + 32768 + ldsOff);                           \
    gload_lds16(gB + K64r + (kt), (buf) + 40960 + ldsOff);                    \
    gload_lds16(gB + 2 * K64r + (kt), (buf) + 49152 + ldsOff);                \
    gload_lds16(gB + 3 * K64r + (kt), (buf) + 57344 + ldsOff);                \
  } while (0)

  // asm ds_read addresses (byte offsets in LDS address space)
  const u32 ldsbase = (u32)(uintptr_t)(__attribute__((address_space(3))) char*)lds;
  const u32 cb0 = (u32)((fc << 4) ^ sw);
  const u32 cb1 = cb0 ^ 64u;
  const u32 aB0 = ldsbase + (u32)((wm * 128 + fr) * 128) + cb0;
  const u32 aB1 = ldsbase + (u32)((wm * 128 + fr) * 128) + cb1;
  const u32 bB0 = ldsbase + 32768u + (u32)((wn * 64 + fr) * 128) + cb0;
  const u32 bB1 = ldsbase + 32768u + (u32)((wn * 64 + fr) * 128) + cb1;

#define DSR(dst, ad, off) \
  asm volatile("ds_read_b128 %0, %1 offset:" off : "=v"(dst) : "v"(ad))

#define LOAD_A0(dst) do { \
  DSR(dst[0][0], aC0, "0");    DSR(dst[0][1], aC1, "0");    \
  DSR(dst[1][0], aC0, "2048"); DSR(dst[1][1], aC1, "2048"); \
  DSR(dst[2][0], aC0, "4096"); DSR(dst[2][1], aC1, "4096"); \
  DSR(dst[3][0], aC0, "6144"); DSR(dst[3][1], aC1, "6144"); } while (0)
#define LOAD_A1(dst) do { \
  DSR(dst[0][0], aC0, "8192");  DSR(dst[0][1], aC1, "8192");  \
  DSR(dst[1][0], aC0, "10240"); DSR(dst[1][1], aC1, "10240"); \
  DSR(dst[2][0], aC0, "12288"); DSR(dst[2][1], aC1, "12288"); \
  DSR(dst[3][0], aC0, "14336"); DSR(dst[3][1], aC1, "14336"); } while (0)
#define LOAD_B0() do { \
  DSR(b0[0][0], bC0, "0");    DSR(b0[0][1], bC1, "0");    \
  DSR(b0[1][0], bC0, "2048"); DSR(b0[1][1], bC1, "2048"); } while (0)
#define LOAD_B1() do { \
  DSR(b1[0][0], bC0, "4096"); DSR(b1[0][1], bC1, "4096"); \
  DSR(b1[1][0], bC0, "6144"); DSR(b1[1][1], bC1, "6144"); } while (0)

#define MMA(qm, qn, af, bf)                                                  \
  _Pragma("unroll") for (int j_ = 0; j_ < 4; ++j_)                           \
  _Pragma("unroll") for (int n_ = 0; n_ < 2; ++n_)                           \
  _Pragma("unroll") for (int k_ = 0; k_ < 2; ++k_)                           \
    acc[(qm) * 4 + j_][(qn) * 2 + n_] = __builtin_amdgcn_mfma_f32_16x16x32_bf16( \
        af[j_][k_], bf[n_][k_], acc[(qm) * 4 + j_][(qn) * 2 + n_], 0, 0, 0);

  f32x4 acc[8][4];
  f32x4 zero = {0.0f, 0.0f, 0.0f, 0.0f};
#pragma unroll
  for (int m = 0; m < 8; ++m)
#pragma unroll
    for (int n = 0; n < 4; ++n) acc[m][n] = zero;

  const int NT = K / BK;

  // prologue: tile 0 -> buf0
  STAGE_A4(lds, 0);
  STAGE_B4(lds, 0);
  asm volatile("s_waitcnt vmcnt(0)" ::: "memory");
  __builtin_amdgcn_s_barrier();

  bf16x8 a[4][2], a2[4][2], b0[2][2], b1[2][2];
  int cur = 0;
  for (int t = 0; t < NT; ++t) {
    const u32 bo = (u32)(cur << 16);
    const u32 aC0 = aB0 + bo, aC1 = aB1 + bo;
    const u32 bC0 = bB0 + bo, bC1 = bB1 + bo;
    char* bq = lds + (cur ^ 1) * 65536;   // tile t+1's buffer
    const int kt1 = (t + 1) * BK;
    const int st1 = (t + 1 < NT);

    // cluster 1: frags for quads (0,0),(0,1); stage t+1 A
    LOAD_A0(a);
    LOAD_B0();
    LOAD_B1();
    if (st1) STAGE_A4(bq, kt1);
    asm volatile("s_waitcnt lgkmcnt(0)" ::: "memory");
    __builtin_amdgcn_sched_barrier(0);
    __builtin_amdgcn_s_setprio(1);
    MMA(0, 0, a, b0);
    MMA(0, 1, a, b1);
    __builtin_amdgcn_s_setprio(0);
    __builtin_amdgcn_sched_barrier(0);

    // cluster 2: second A half into separate regs (no WAR with cluster 1);
    // stage t+1 B
    LOAD_A1(a2);
    if (st1) STAGE_B4(bq, kt1);
    asm volatile("s_waitcnt lgkmcnt(0)" ::: "memory");
    __builtin_amdgcn_sched_barrier(0);
    __builtin_amdgcn_s_setprio(1);
    MMA(1, 1, a2, b1);
    MMA(1, 0, a2, b0);
    __builtin_amdgcn_s_setprio(0);
    __builtin_amdgcn_sched_barrier(0);

    // tile boundary: retire t+1's stages (issued ~1 tile ago), then the ONE
    // block-wide barrier: buffer handoff for both directions.
    asm volatile("s_waitcnt vmcnt(0)" ::: "memory");
    __builtin_amdgcn_s_barrier();
    __builtin_amdgcn_sched_barrier(0);
    cur ^= 1;
  }

  // epilogue: y = acc * (g_x * g_w) + bias
  float gs = (scal[0] / 2688.0f) * (scal[1] / 2688.0f);
#pragma unroll
  for (int n = 0; n < 4; ++n) {
    int col = bcol + wn * 64 + n * 16 + fr;        // C/D: col = lane&15
    float bv = bias[col];
#pragma unroll
    for (int m = 0; m < 8; ++m) {
      int row0 = brow + wm * 128 + m * 16 + (fc << 2);  // row = (lane>>4)*4 + j
      f32x4 v = acc[m][n];
#pragma unroll
      for (int j = 0; j < 4; ++j)
        out[(size_t)(row0 + j) * N + col] = v[j] * gs + bv;
    }
  }
}

// ---------- launch ----------

extern "C" void kernel_launch(void* const* d_in, const int* in_sizes, int n_in,
                              void* d_out, int out_size, void* d_ws, size_t ws_size,
                              hipStream_t stream) {
  const float* x = (const float*)d_in[0];
  const float* w = (const float*)d_in[1];
  const float* bias = (const float*)d_in[2];
  float* out = (float*)d_out;

  const int DOUT = in_sizes[2];        // 4096
  const int K = in_sizes[1] / DOUT;    // 4096
  const int M = in_sizes[0] / K;       // 8192
  const int N = DOUT;

  // ws layout: [0,8): scal; [256, +8KB): px; then pw (2KB); qw at 32768; qx after
  float* scal = (float*)d_ws;
  float* px = (float*)((char*)d_ws + 256);          // 2048 floats
  float* pw = px + 2048;                            // 512 floats
  u16* qw = (u16*)((char*)d_ws + 32768);
  u16* qx = (u16*)((char*)d_ws + 32768 + (size_t)N * K * 2);

  // pass 1: both amax partial reductions in ONE launch
  amax_merged_kernel<<<AMX_XB + AMX_WB, 256, 0, stream>>>(
      (const float4*)x, (M * K) / 4, (const float4*)w, (N * K) / 4, px, pw);
  finalize_kernel<<<1, 256, 0, stream>>>(px, pw, scal, AMX_XB, AMX_WB);

  // pass 2: both quantizations in ONE launch
  int nxblocks = (M * K) / 16 / 256;               // 8192
  int nwblocks = (N / 16) * (K / 16) / 4;          // 16384
  quant_merged_kernel<<<nxblocks + nwblocks, 256, 0, stream>>>(
      x, w, scal, qx, qw, nxblocks, K / 16, K);

  gemm_kernel<<<(M / BM) * (N / BN), 512, 131072, stream>>>(qx, qw, bias, scal, out,
                                                            M, N, K);
}